// Round 8
// baseline (233.077 us; speedup 1.0000x reference)
//
#include <hip/hip_runtime.h>
#include <math.h>

#define B_ 32
#define Q_ 1024
#define G_ 64
#define T_ 256    // build threads (4 waves); matcher runs on wave 0 only
#define K16 16    // columns per lane in matcher (Q_ / 64)
#define LROWS 32  // cost rows resident in LDS

// ---- cross-lane helpers -------------------------------------------------
// row_ror:N DPP rotates within each 16-lane row; all source lanes valid.
template<int CTRL>
__device__ __forceinline__ int dpp_i32(int x) {
    return __builtin_amdgcn_update_dpp(x, x, CTRL, 0xF, 0xF, false);
}
template<int CTRL>
__device__ __forceinline__ double dpp_f64(double x) {
    union { double d; int i[2]; } a; a.d = x;
    union { int i[2]; double d; } r;
    r.i[0] = __builtin_amdgcn_update_dpp(a.i[0], a.i[0], CTRL, 0xF, 0xF, false);
    r.i[1] = __builtin_amdgcn_update_dpp(a.i[1], a.i[1], CTRL, 0xF, 0xF, false);
    return r.d;
}
#define ROR1 0x121
#define ROR2 0x122
#define ROR4 0x124
#define ROR8 0x128

__device__ __forceinline__ double readlane_f64(double x, int sl) {
    const int s = __builtin_amdgcn_readfirstlane(sl);
    union { double d; int i2[2]; } a; a.d = x;
    union { int i2[2]; double d; } r;
    r.i2[0] = __builtin_amdgcn_readlane(a.i2[0], s);
    r.i2[1] = __builtin_amdgcn_readlane(a.i2[1], s);
    return r.d;
}
__device__ __forceinline__ int readlane_i32(int x, int sl) {
    return __builtin_amdgcn_readlane(x, __builtin_amdgcn_readfirstlane(sl));
}
// uniform-index select from a 16-entry register array
__device__ __forceinline__ int sel16(const int* p, int s) {
    int v = p[0];
    #pragma unroll
    for (int k = 1; k < K16; ++k) v = (s == k) ? p[k] : v;
    return v;
}

// Fused: 256-thread build (rows<32 -> LDS ldsct; rows>=32 -> same-XCD ctg via
// tile), then SINGLE-WAVE Jonker-Volgenant (zero barriers in hot loop).
// Lane l owns columns j = l + 64k (k<16): v, shortest, path, SC-bit, asg-bit,
// costs in registers. Lane l owns u[row=l] and col4row[row=l] in registers.
template<bool HASWS>
__global__ __launch_bounds__(256) void matcher_fused(
    const float* __restrict__ obj, const float* __restrict__ cd,
    const float* __restrict__ gi, const int* __restrict__ ngt,
    float* __restrict__ ctg, float* __restrict__ out_ind,
    float* __restrict__ out_mask)
{
    __shared__ float ldsct[LROWS * 1025];            // 131200 B, 2-way banks: free
    __shared__ int   row4col_[Q_];                   // hops + final output
    __shared__ __align__(16) char scratch_[LROWS * 65 * 4]; // tile (build) / sh dump

    float (*tile)[65] = (float (*)[65])scratch_;
    double* sh_lds    = (double*)scratch_;

    const int b = blockIdx.x;
    const int t = threadIdx.x;
    const int l = t & 63;
    const int w = t >> 6;
    const int g = ngt[b];

    const float* objb = obj + (b << 10);
    const float* cdb  = cd + ((size_t)b << 16);
    const float* gib  = gi + ((size_t)b << 16);
    float* ctgb = HASWS ? (ctg + ((size_t)b << 15)) : (float*)nullptr;

    for (int j = t; j < Q_; j += T_) row4col_[j] = -1;

    // ---- build: all 256 threads; rows<32 direct to LDS, rows>=32 via tile ----
    if (g > 0) {
        const float4* cd4 = (const float4*)cdb;
        const float4* gi4 = (const float4*)gib;
        for (int jb = 0; jb < Q_; jb += 64) {
            #pragma unroll
            for (int p = 0; p < 4; ++p) {
                const int f  = t + (p << 8);
                const int jj = f >> 4;          // 0..63
                const int q  = f & 15;          // i-quad
                const int i0 = q << 2;          // 0,4,..,60
                const int j  = jb + jj;
                const float om = __fmul_rn(5.0f, -objb[j]);
                const float4 c4 = cd4[(j << 4) + q];
                const float4 q4 = gi4[(j << 4) + q];
                const float r0 = __fadd_rn(__fadd_rn(om, __fmul_rn(10.0f, c4.x)), __fmul_rn(2.0f, -q4.x));
                const float r1 = __fadd_rn(__fadd_rn(om, __fmul_rn(10.0f, c4.y)), __fmul_rn(2.0f, -q4.y));
                const float r2 = __fadd_rn(__fadd_rn(om, __fmul_rn(10.0f, c4.z)), __fmul_rn(2.0f, -q4.z));
                const float r3 = __fadd_rn(__fadd_rn(om, __fmul_rn(10.0f, c4.w)), __fmul_rn(2.0f, -q4.w));
                if (i0 < LROWS) {               // 2-way bank alias: free
                    ldsct[(i0 + 0) * 1025 + j] = r0;
                    ldsct[(i0 + 1) * 1025 + j] = r1;
                    ldsct[(i0 + 2) * 1025 + j] = r2;
                    ldsct[(i0 + 3) * 1025 + j] = r3;
                } else if (HASWS) {
                    tile[i0 - LROWS + 0][jj] = r0;
                    tile[i0 - LROWS + 1][jj] = r1;
                    tile[i0 - LROWS + 2][jj] = r2;
                    tile[i0 - LROWS + 3][jj] = r3;
                }
            }
            __syncthreads();
            if (HASWS) {
                #pragma unroll
                for (int r = 0; r < 8; ++r) {   // 32 rows x 64 cols / 256 thr
                    const int idx = (r << 8) + t;
                    const int i2 = idx >> 6, j2 = idx & 63;   // ctg row i2 = global row LROWS+i2
                    if (LROWS + i2 < g)
                        ctgb[(i2 << 10) + jb + j2] = tile[i2][j2];   // coalesced
                }
            }
            __syncthreads();
        }
    }

    // ---- matcher: wave 0 only, zero barriers in the hot loop ----
    if (w == 0 && g > 0) {
        float objm[K16];
        if (!HASWS) {
            #pragma unroll
            for (int k = 0; k < K16; ++k) objm[k] = __fmul_rn(5.0f, -objb[l + (k << 6)]);
        }
        auto load_row = [&](int i, float* c) {
            if (i < LROWS) {
                #pragma unroll
                for (int k = 0; k < K16; ++k) c[k] = ldsct[i * 1025 + l + (k << 6)];
            } else if (HASWS) {
                #pragma unroll
                for (int k = 0; k < K16; ++k) c[k] = ctgb[((i - LROWS) << 10) + l + (k << 6)];
            } else {
                #pragma unroll
                for (int k = 0; k < K16; ++k) {
                    const int j = l + (k << 6);
                    const int idx = (j << 6) + i;
                    c[k] = __fadd_rn(__fadd_rn(objm[k], __fmul_rn(10.0f, cdb[idx])),
                                     __fmul_rn(2.0f, -gib[idx]));
                }
            }
        };
        // lex-min reduce over cand[16] per lane -> uniform (mv, mj) in all lanes
        auto lexmin = [&](const double* cand, double& mv_out, int& mj_out) {
            double tv[8]; int tk[8];
            #pragma unroll
            for (int m = 0; m < 8; ++m) {
                const bool s = cand[2 * m + 1] < cand[2 * m];
                tv[m] = s ? cand[2 * m + 1] : cand[2 * m];
                tk[m] = s ? 2 * m + 1 : 2 * m;
            }
            #pragma unroll
            for (int m = 0; m < 4; ++m) {
                const bool s = tv[2 * m + 1] < tv[2 * m];
                tv[m] = s ? tv[2 * m + 1] : tv[2 * m];
                tk[m] = s ? tk[2 * m + 1] : tk[2 * m];
            }
            #pragma unroll
            for (int m = 0; m < 2; ++m) {
                const bool s = tv[2 * m + 1] < tv[2 * m];
                tv[m] = s ? tv[2 * m + 1] : tv[2 * m];
                tk[m] = s ? tk[2 * m + 1] : tk[2 * m];
            }
            const bool s0 = tv[1] < tv[0];
            double bv = s0 ? tv[1] : tv[0];
            int    bj = l + ((s0 ? tk[1] : tk[0]) << 6);
            #pragma unroll
            for (int rr = 0; rr < 4; ++rr) {
                double ov; int oj;
                if (rr == 0)      { ov = dpp_f64<ROR1>(bv); oj = dpp_i32<ROR1>(bj); }
                else if (rr == 1) { ov = dpp_f64<ROR2>(bv); oj = dpp_i32<ROR2>(bj); }
                else if (rr == 2) { ov = dpp_f64<ROR4>(bv); oj = dpp_i32<ROR4>(bj); }
                else              { ov = dpp_f64<ROR8>(bv); oj = dpp_i32<ROR8>(bj); }
                const bool take = (ov < bv) || (ov == bv && oj < bj);
                bv = take ? ov : bv;
                bj = take ? oj : bj;
            }
            double wv = readlane_f64(bv, 0);
            int    wj = readlane_i32(bj, 0);
            #pragma unroll
            for (int gg = 1; gg < 4; ++gg) {
                const double ov = readlane_f64(bv, gg << 4);
                const int    oj = readlane_i32(bj, gg << 4);
                const bool take = (ov < wv) || (ov == wv && oj < wj);
                wv = take ? ov : wv;
                wj = take ? oj : wj;
            }
            mv_out = wv; mj_out = wj;
        };

        const double INF = __builtin_inf();
        double u_rep   = 0.0;     // u[l]
        int    c4r_rep = -1;      // col4row[l]
        unsigned asg   = 0u;      // bit k: column l+64k assigned
        double v_r[K16];
        double sh_r[K16];
        int    path_r[K16];
        float  c_row[K16], c_next[K16];
        #pragma unroll
        for (int k = 0; k < K16; ++k) { v_r[k] = 0.0; path_r[k] = 0; }

        load_row(0, c_next);    // prime the pipeline

        for (int cur = 0; cur < g; ++cur) {
            #pragma unroll
            for (int k = 0; k < K16; ++k) c_row[k] = c_next[k];   // prefetched
            unsigned sc = 0u;
            bool inSR = (l == cur);
            int nSR = 1;
            double minv;
            int i = cur;
            int sink = -1;
            double ui = readlane_f64(u_rep, i);
            int jm;

            // ---- fast first step: shortest=INF, SC empty -> unconditional ----
            {
                double cand[K16];
                #pragma unroll
                for (int k = 0; k < K16; ++k) {
                    const double r = ((0.0 + (double)c_row[k]) - ui) - v_r[k];
                    sh_r[k] = r;
                    path_r[k] = cur;
                    cand[k] = r;
                }
                lexmin(cand, minv, jm);
                if (l == (jm & 63)) sc |= 1u << (jm >> 6);
                const unsigned oa = (unsigned)readlane_i32((int)asg, jm & 63);
                if (!((oa >> (jm >> 6)) & 1u)) {
                    sink = jm;
                } else {
                    i = row4col_[jm];
                    if (l == i) inSR = true;
                    ui = readlane_f64(u_rep, i);
                    load_row(i, c_row);
                }
            }
            // ---- slow steps (rare) ----
            while (sink < 0) {
                ++nSR;
                double cand[K16];
                #pragma unroll
                for (int k = 0; k < K16; ++k) {
                    const double r = ((minv + (double)c_row[k]) - ui) - v_r[k];
                    const bool notSC = !((sc >> k) & 1u);
                    const bool upd = notSC && (r < sh_r[k]);   // strict <
                    sh_r[k]   = upd ? r : sh_r[k];
                    path_r[k] = upd ? i : path_r[k];
                    cand[k] = notSC ? sh_r[k] : INF;
                }
                lexmin(cand, minv, jm);
                if (l == (jm & 63)) sc |= 1u << (jm >> 6);
                const unsigned oa = (unsigned)readlane_i32((int)asg, jm & 63);
                if (!((oa >> (jm >> 6)) & 1u)) {
                    sink = jm;
                } else {
                    i = row4col_[jm];
                    if (l == i) inSR = true;
                    ui = readlane_f64(u_rep, i);
                    load_row(i, c_row);
                }
            }

            // ---- dual updates (reference order) ----
            if (l == cur) u_rep += minv;
            if (nSR > 1) {
                #pragma unroll
                for (int k = 0; k < K16; ++k) sh_lds[l + (k << 6)] = sh_r[k];
                __builtin_amdgcn_wave_barrier();
                if (inSR && l != cur) u_rep += minv - sh_lds[c4r_rep];
                __builtin_amdgcn_wave_barrier();
            }
            #pragma unroll
            for (int k = 0; k < K16; ++k) {
                const double nv = v_r[k] - (minv - sh_r[k]);
                v_r[k] = ((sc >> k) & 1u) ? nv : v_r[k];
            }

            // prefetch next row (LDS or same-XCD global); latency hides behind augment
            if (cur + 1 < g) load_row(cur + 1, c_next);

            // ---- augment (registers + readlanes; 1 LDS write per node) ----
            {
                int j = sink;
                while (true) {
                    const int so = j & 63, ss = j >> 6;
                    const int ii = readlane_i32(sel16(path_r, ss), so);
                    const int nj = readlane_i32(c4r_rep, ii);   // old col4row[ii]
                    if (l == 0) row4col_[j] = ii;
                    if (l == so) asg |= 1u << ss;
                    if (l == ii) c4r_rep = j;
                    j = nj;
                    if (ii == cur) break;
                }
            }
            __builtin_amdgcn_wave_barrier();
        }
    }

    __syncthreads();   // waves 1-3 park here; wave 0 arrives after matching
    for (int j = t; j < Q_; j += T_) {
        const int rc = row4col_[j];
        out_ind [(b << 10) + j] = (rc >= 0) ? (float)rc : 0.0f;
        out_mask[(b << 10) + j] = (rc >= 0) ? 1.0f : 0.0f;
    }
}

extern "C" void kernel_launch(void* const* d_in, const int* in_sizes, int n_in,
                              void* d_out, int out_size, void* d_ws, size_t ws_size,
                              hipStream_t stream)
{
    const float* obj = (const float*)d_in[1];
    const float* cd  = (const float*)d_in[2];
    const float* gi  = (const float*)d_in[3];
    const int*   ngt = (const int*)d_in[4];
    float* out0 = (float*)d_out;
    float* out1 = out0 + B_ * Q_;

    const size_t need = (size_t)B_ * (G_ - LROWS) * Q_ * sizeof(float);  // 4 MB
    if (ws_size >= need) {
        matcher_fused<true><<<B_, T_, 0, stream>>>(obj, cd, gi, ngt,
                                                   (float*)d_ws, out0, out1);
    } else {
        matcher_fused<false><<<B_, T_, 0, stream>>>(obj, cd, gi, ngt,
                                                    nullptr, out0, out1);
    }
}

// Round 9
// 196.332 us; speedup vs baseline: 1.1872x; 1.1872x over previous
//
#include <hip/hip_runtime.h>
#include <math.h>

#define B_ 32
#define Q_ 1024
#define G_ 64
#define T_ 256    // build threads (4 waves); matcher runs on wave 0 only
#define K16 16    // columns per lane in matcher (Q_ / 64)
#define LROWS 32  // cost rows resident in LDS

// ---- cross-lane helpers -------------------------------------------------
template<int CTRL>
__device__ __forceinline__ int dpp_i32(int x) {
    return __builtin_amdgcn_update_dpp(x, x, CTRL, 0xF, 0xF, false);
}
template<int CTRL>
__device__ __forceinline__ double dpp_f64(double x) {
    union { double d; int i[2]; } a; a.d = x;
    union { int i[2]; double d; } r;
    r.i[0] = __builtin_amdgcn_update_dpp(a.i[0], a.i[0], CTRL, 0xF, 0xF, false);
    r.i[1] = __builtin_amdgcn_update_dpp(a.i[1], a.i[1], CTRL, 0xF, 0xF, false);
    return r.d;
}
#define ROR1 0x121
#define ROR2 0x122
#define ROR4 0x124
#define ROR8 0x128

__device__ __forceinline__ double readlane_f64(double x, int sl) {
    const int s = __builtin_amdgcn_readfirstlane(sl);
    union { double d; int i2[2]; } a; a.d = x;
    union { int i2[2]; double d; } r;
    r.i2[0] = __builtin_amdgcn_readlane(a.i2[0], s);
    r.i2[1] = __builtin_amdgcn_readlane(a.i2[1], s);
    return r.d;
}
__device__ __forceinline__ int readlane_i32(int x, int sl) {
    return __builtin_amdgcn_readlane(x, __builtin_amdgcn_readfirstlane(sl));
}
// uniform-index select from a 16-entry register array
__device__ __forceinline__ int sel16(const int* p, int s) {
    int v = p[0];
    #pragma unroll
    for (int k = 1; k < K16; ++k) v = (s == k) ? p[k] : v;
    return v;
}

// Fused: 256-thread cost build (rows<32 -> LDS; rows>=32 -> same-XCD ctg),
// then SINGLE-WAVE Jonker-Volgenant with a 1-step fast path:
//   u[cur]==0 at row start (only assigned rows' u ever updated), and a
//   1-step row leaves v unchanged (v[SC] -= minv - shortest[SC] == 0),
//   so the common row is: r_k = (f64)c_k - v_k; argmin; asg test; O(1) assign.
// Argmin = fmin value-reduce (v_min_f64 + DPP) then eq-mask + __ffs + min_u32
// index-reduce: ties -> smallest j, exactly np.argmin (eq treats -0==+0).
template<bool HASWS>
__global__ __launch_bounds__(256) void matcher_fused(
    const float* __restrict__ obj, const float* __restrict__ cd,
    const float* __restrict__ gi, const int* __restrict__ ngt,
    float* __restrict__ ctg, float* __restrict__ out_ind,
    float* __restrict__ out_mask)
{
    __shared__ float ldsct[LROWS * 1025];            // 2-way bank alias: free
    __shared__ int   row4col_[Q_];                   // hops + final output
    __shared__ __align__(16) char scratch_[LROWS * 65 * 4]; // tile (build) / sh dump

    float (*tile)[65] = (float (*)[65])scratch_;
    double* sh_lds    = (double*)scratch_;

    const int b = blockIdx.x;
    const int t = threadIdx.x;
    const int l = t & 63;
    const int w = t >> 6;
    const int g = ngt[b];

    const float* objb = obj + (b << 10);
    const float* cdb  = cd + ((size_t)b << 16);
    const float* gib  = gi + ((size_t)b << 16);
    float* ctgb = HASWS ? (ctg + ((size_t)b << 15)) : (float*)nullptr;

    for (int j = t; j < Q_; j += T_) row4col_[j] = -1;

    // ---- build: all 256 threads; rows<32 direct to LDS, rows>=32 via tile ----
    if (g > 0) {
        const float4* cd4 = (const float4*)cdb;
        const float4* gi4 = (const float4*)gib;
        for (int jb = 0; jb < Q_; jb += 64) {
            #pragma unroll
            for (int p = 0; p < 4; ++p) {
                const int f  = t + (p << 8);
                const int jj = f >> 4;          // 0..63
                const int q  = f & 15;          // i-quad
                const int i0 = q << 2;          // 0,4,..,60
                const int j  = jb + jj;
                const float om = __fmul_rn(5.0f, -objb[j]);
                const float4 c4 = cd4[(j << 4) + q];
                const float4 q4 = gi4[(j << 4) + q];
                const float r0 = __fadd_rn(__fadd_rn(om, __fmul_rn(10.0f, c4.x)), __fmul_rn(2.0f, -q4.x));
                const float r1 = __fadd_rn(__fadd_rn(om, __fmul_rn(10.0f, c4.y)), __fmul_rn(2.0f, -q4.y));
                const float r2 = __fadd_rn(__fadd_rn(om, __fmul_rn(10.0f, c4.z)), __fmul_rn(2.0f, -q4.z));
                const float r3 = __fadd_rn(__fadd_rn(om, __fmul_rn(10.0f, c4.w)), __fmul_rn(2.0f, -q4.w));
                if (i0 < LROWS) {
                    ldsct[(i0 + 0) * 1025 + j] = r0;
                    ldsct[(i0 + 1) * 1025 + j] = r1;
                    ldsct[(i0 + 2) * 1025 + j] = r2;
                    ldsct[(i0 + 3) * 1025 + j] = r3;
                } else if (HASWS) {
                    tile[i0 - LROWS + 0][jj] = r0;
                    tile[i0 - LROWS + 1][jj] = r1;
                    tile[i0 - LROWS + 2][jj] = r2;
                    tile[i0 - LROWS + 3][jj] = r3;
                }
            }
            __syncthreads();
            if (HASWS) {
                #pragma unroll
                for (int r = 0; r < 8; ++r) {   // 32 rows x 64 cols / 256 thr
                    const int idx = (r << 8) + t;
                    const int i2 = idx >> 6, j2 = idx & 63;
                    if (LROWS + i2 < g)
                        ctgb[(i2 << 10) + jb + j2] = tile[i2][j2];   // coalesced
                }
            }
            __syncthreads();
        }
    }

    // ---- matcher: wave 0 only, zero barriers in the hot loop ----
    if (w == 0 && g > 0) {
        float objm[K16];
        if (!HASWS) {
            #pragma unroll
            for (int k = 0; k < K16; ++k) objm[k] = __fmul_rn(5.0f, -objb[l + (k << 6)]);
        }
        auto load_row = [&](int i, float* c) {
            if (i < LROWS) {
                #pragma unroll
                for (int k = 0; k < K16; ++k) c[k] = ldsct[i * 1025 + l + (k << 6)];
            } else if (HASWS) {
                #pragma unroll
                for (int k = 0; k < K16; ++k) c[k] = ctgb[((i - LROWS) << 10) + l + (k << 6)];
            } else {
                #pragma unroll
                for (int k = 0; k < K16; ++k) {
                    const int j = l + (k << 6);
                    const int idx = (j << 6) + i;
                    c[k] = __fadd_rn(__fadd_rn(objm[k], __fmul_rn(10.0f, cdb[idx])),
                                     __fmul_rn(2.0f, -gib[idx]));
                }
            }
        };
        // argmin over cand[16]x64lanes: value via fmin tree/DPP, index via
        // eq-mask + ffs + min_u32. Ties -> smallest j (= k-major, lane-minor).
        auto lexmin = [&](const double* cand, double& gv_o, int& jm_o) {
            double t8[8];
            #pragma unroll
            for (int m = 0; m < 8; ++m) t8[m] = fmin(cand[2 * m], cand[2 * m + 1]);
            double t4a = fmin(t8[0], t8[1]), t4b = fmin(t8[2], t8[3]);
            double t4c = fmin(t8[4], t8[5]), t4d = fmin(t8[6], t8[7]);
            double bv = fmin(fmin(t4a, t4b), fmin(t4c, t4d));
            bv = fmin(bv, dpp_f64<ROR1>(bv));
            bv = fmin(bv, dpp_f64<ROR2>(bv));
            bv = fmin(bv, dpp_f64<ROR4>(bv));
            bv = fmin(bv, dpp_f64<ROR8>(bv));
            const double g0 = readlane_f64(bv, 0),  g1 = readlane_f64(bv, 16);
            const double g2 = readlane_f64(bv, 32), g3 = readlane_f64(bv, 48);
            const double gv = fmin(fmin(g0, g1), fmin(g2, g3));
            unsigned msk = 0u;
            #pragma unroll
            for (int k = 0; k < K16; ++k) msk |= (cand[k] == gv) ? (1u << k) : 0u;
            int j = msk ? (((__ffs((int)msk) - 1) << 6) | l) : 0x7fffffff;
            { int o = dpp_i32<ROR1>(j); j = (o < j) ? o : j; }
            { int o = dpp_i32<ROR2>(j); j = (o < j) ? o : j; }
            { int o = dpp_i32<ROR4>(j); j = (o < j) ? o : j; }
            { int o = dpp_i32<ROR8>(j); j = (o < j) ? o : j; }
            int jm = __builtin_amdgcn_readlane(j, 0);
            const int j1 = __builtin_amdgcn_readlane(j, 16);
            const int j2 = __builtin_amdgcn_readlane(j, 32);
            const int j3 = __builtin_amdgcn_readlane(j, 48);
            jm = (j1 < jm) ? j1 : jm;
            jm = (j2 < jm) ? j2 : jm;
            jm = (j3 < jm) ? j3 : jm;
            gv_o = gv; jm_o = jm;
        };

        const double INF = __builtin_inf();
        double u_rep   = 0.0;     // u[l]
        int    c4r_rep = -1;      // col4row[l]
        unsigned asg   = 0u;      // bit k: column l+64k assigned
        double v_r[K16], sh_r[K16];
        int    path_r[K16];
        float  c_row[K16], c_next[K16];
        #pragma unroll
        for (int k = 0; k < K16; ++k) { v_r[k] = 0.0; path_r[k] = 0; }

        load_row(0, c_next);

        for (int cur = 0; cur < g; ++cur) {
            #pragma unroll
            for (int k = 0; k < K16; ++k) c_row[k] = c_next[k];
            if (cur + 1 < g) load_row(cur + 1, c_next);   // hides behind whole row

            // ---- fast first step: u[cur]=0, minv=0 -> r = (f64)c - v ----
            double r[K16];
            #pragma unroll
            for (int k = 0; k < K16; ++k) r[k] = (double)c_row[k] - v_r[k];
            double minv; int jm;
            lexmin(r, minv, jm);
            const int owner0 = jm & 63, slot0 = jm >> 6;
            const unsigned oa0 = (unsigned)readlane_i32((int)asg, owner0);

            if (!((oa0 >> slot0) & 1u)) {
                // ---- 1-step row: O(1) state update (v provably unchanged) ----
                if (l == cur)    { u_rep += minv; c4r_rep = jm; }
                if (l == owner0) asg |= 1u << slot0;
                if (l == 0)      row4col_[jm] = cur;
            } else {
                // ---- slow path: materialize step-1 state, continue standard ----
                unsigned sc = 0u;
                #pragma unroll
                for (int k = 0; k < K16; ++k) { sh_r[k] = r[k]; path_r[k] = cur; }
                if (l == owner0) sc |= 1u << slot0;
                int i = row4col_[jm];
                bool inSR = (l == cur) || (l == i);
                double ui = readlane_f64(u_rep, i);
                load_row(i, c_row);
                int sink = -1;

                while (sink < 0) {
                    double cand[K16];
                    #pragma unroll
                    for (int k = 0; k < K16; ++k) {
                        const double rr = ((minv + (double)c_row[k]) - ui) - v_r[k];
                        const bool notSC = !((sc >> k) & 1u);
                        const bool upd = notSC && (rr < sh_r[k]);   // strict <
                        sh_r[k]   = upd ? rr : sh_r[k];
                        path_r[k] = upd ? i : path_r[k];
                        cand[k] = notSC ? sh_r[k] : INF;
                    }
                    lexmin(cand, minv, jm);
                    if (l == (jm & 63)) sc |= 1u << (jm >> 6);
                    const unsigned oa = (unsigned)readlane_i32((int)asg, jm & 63);
                    if (!((oa >> (jm >> 6)) & 1u)) {
                        sink = jm;
                    } else {
                        i = row4col_[jm];
                        if (l == i) inSR = true;
                        ui = readlane_f64(u_rep, i);
                        load_row(i, c_row);
                    }
                }

                // dual updates (reference order: u, then v, then augment)
                if (l == cur) u_rep += minv;
                #pragma unroll
                for (int k = 0; k < K16; ++k) sh_lds[l + (k << 6)] = sh_r[k];
                __builtin_amdgcn_wave_barrier();
                if (inSR && l != cur) u_rep += minv - sh_lds[c4r_rep];
                __builtin_amdgcn_wave_barrier();
                #pragma unroll
                for (int k = 0; k < K16; ++k) {
                    const double nv = v_r[k] - (minv - sh_r[k]);
                    v_r[k] = ((sc >> k) & 1u) ? nv : v_r[k];
                }

                // augment along alternating path
                int j = sink;
                while (true) {
                    const int so = j & 63, ss = j >> 6;
                    const int ii = readlane_i32(sel16(path_r, ss), so);
                    const int nj = readlane_i32(c4r_rep, ii);   // old col4row[ii]
                    if (l == 0) row4col_[j] = ii;
                    if (l == so) asg |= 1u << ss;
                    if (l == ii) c4r_rep = j;
                    j = nj;
                    if (ii == cur) break;
                }
                __builtin_amdgcn_wave_barrier();
            }
        }
    }

    __syncthreads();   // waves 1-3 park here; wave 0 arrives after matching
    for (int j = t; j < Q_; j += T_) {
        const int rc = row4col_[j];
        out_ind [(b << 10) + j] = (rc >= 0) ? (float)rc : 0.0f;
        out_mask[(b << 10) + j] = (rc >= 0) ? 1.0f : 0.0f;
    }
}

extern "C" void kernel_launch(void* const* d_in, const int* in_sizes, int n_in,
                              void* d_out, int out_size, void* d_ws, size_t ws_size,
                              hipStream_t stream)
{
    const float* obj = (const float*)d_in[1];
    const float* cd  = (const float*)d_in[2];
    const float* gi  = (const float*)d_in[3];
    const int*   ngt = (const int*)d_in[4];
    float* out0 = (float*)d_out;
    float* out1 = out0 + B_ * Q_;

    const size_t need = (size_t)B_ * (G_ - LROWS) * Q_ * sizeof(float);  // 4 MB
    if (ws_size >= need) {
        matcher_fused<true><<<B_, T_, 0, stream>>>(obj, cd, gi, ngt,
                                                   (float*)d_ws, out0, out1);
    } else {
        matcher_fused<false><<<B_, T_, 0, stream>>>(obj, cd, gi, ngt,
                                                    nullptr, out0, out1);
    }
}